// Round 1
// baseline (10151.291 us; speedup 1.0000x reference)
//
#include <hip/hip_runtime.h>
#include <math.h>

#define HD 300
#define BB 64
#define LL 20
#define PP 8
#define NN 32768
#define EE 262144
#define CC 2048
#define OUTD 1845
#define NPG 512
#define EPG 4096
#define H4 1200
#define H2 600
#define CE 2049

__device__ __forceinline__ float blockReduce(float v, float* sbuf, int op) {
  int t = threadIdx.x, lane = t & 63, wave = t >> 6, nw = (blockDim.x + 63) >> 6;
  #pragma unroll
  for (int o = 32; o; o >>= 1) {
    float u = __shfl_down(v, o, 64);
    v = op ? fmaxf(v, u) : (v + u);
  }
  if (lane == 0) sbuf[wave] = v;
  __syncthreads();
  float r;
  if (op) { r = sbuf[0]; for (int w2 = 1; w2 < nw; ++w2) r = fmaxf(r, sbuf[w2]); }
  else { r = 0.f; for (int w2 = 0; w2 < nw; ++w2) r += sbuf[w2]; }
  __syncthreads();
  return r;
}

// ---------------- generic tiled GEMM: C = act(A @ B(^T) + bias) ----------------
// TRANS_B=1: B is (N,K) row-major (i.e. C = A @ B^T). ACT: 0 none, 1 ELU.
template<int TRANS_B, int ACT>
__global__ void gemm_tile(const float* __restrict__ A, int lda,
                          const float* __restrict__ B, int ldb,
                          const float* __restrict__ bias,
                          float* __restrict__ C, int ldc,
                          int M, int N, int K) {
  __shared__ float As[32][33];
  __shared__ float Bs[32][33];
  const int tid = threadIdx.x;
  const int tx = tid & 15, ty = tid >> 4;
  const int m0 = blockIdx.y * 32, n0 = blockIdx.x * 32;
  float acc00 = 0.f, acc01 = 0.f, acc10 = 0.f, acc11 = 0.f;
  for (int k0 = 0; k0 < K; k0 += 32) {
    for (int i = tid; i < 1024; i += 256) {
      int r = i >> 5, c = i & 31;
      int m = m0 + r, k = k0 + c;
      As[r][c] = (m < M && k < K) ? A[(size_t)m * lda + k] : 0.f;
    }
    if (TRANS_B) {
      for (int i = tid; i < 1024; i += 256) {
        int r = i >> 5, c = i & 31;   // r = n-within-tile, c = k-within-tile
        int n = n0 + r, k = k0 + c;
        Bs[c][r] = (n < N && k < K) ? B[(size_t)n * ldb + k] : 0.f;
      }
    } else {
      for (int i = tid; i < 1024; i += 256) {
        int r = i >> 5, c = i & 31;   // r = k, c = n
        int n = n0 + c, k = k0 + r;
        Bs[r][c] = (n < N && k < K) ? B[(size_t)k * ldb + n] : 0.f;
      }
    }
    __syncthreads();
    #pragma unroll
    for (int kk = 0; kk < 32; ++kk) {
      float a0 = As[ty * 2][kk], a1 = As[ty * 2 + 1][kk];
      float b0 = Bs[kk][tx * 2], b1 = Bs[kk][tx * 2 + 1];
      acc00 += a0 * b0; acc01 += a0 * b1; acc10 += a1 * b0; acc11 += a1 * b1;
    }
    __syncthreads();
  }
  float accs[2][2] = {{acc00, acc01}, {acc10, acc11}};
  #pragma unroll
  for (int i = 0; i < 2; ++i) {
    #pragma unroll
    for (int j = 0; j < 2; ++j) {
      int m = m0 + ty * 2 + i, n = n0 + tx * 2 + j;
      if (m < M && n < N) {
        float v = accs[i][j] + (bias ? bias[n] : 0.f);
        if (ACT == 1) v = v > 0.f ? v : expm1f(v);
        C[(size_t)m * ldc + n] = v;
      }
    }
  }
}

// ---------------- small utility kernels ----------------
__global__ void zero_kernel(float* p, int n) {
  int i = blockIdx.x * 256 + threadIdx.x;
  if (i < n) p[i] = 0.f;
}

__global__ void init_dist_kernel(float* dist) {
  int i = blockIdx.x * 256 + threadIdx.x;
  if (i < NN) dist[i] = 1.f / (float)NPG;
}

__global__ void build_ve_kernel(float* ve, const float* __restrict__ cv,
                                const float* __restrict__ demb) {
  int i = blockIdx.x * 256 + threadIdx.x;
  if (i >= CE * HD) return;
  int row = i / HD;
  ve[i] = (row < CC) ? cv[i] : demb[i - CC * HD];
}

__global__ void softmax_rows_kernel(float* __restrict__ x, float* __restrict__ lastcol, int len) {
  int row = blockIdx.x, t = threadIdx.x;
  float* p = x + (size_t)row * len;
  __shared__ float sbuf[8];
  float m = -1e30f;
  for (int i = t; i < len; i += blockDim.x) m = fmaxf(m, p[i]);
  m = blockReduce(m, sbuf, 1);
  float s = 0.f;
  for (int i = t; i < len; i += blockDim.x) { float e = expf(p[i] - m); p[i] = e; s += e; }
  s = blockReduce(s, sbuf, 0);
  float inv = 1.f / s;
  for (int i = t; i < len; i += blockDim.x) {
    float v = p[i] * inv;
    p[i] = v;
    if (lastcol && i == len - 1) lastcol[row] = v;
  }
}

__global__ void tagged_addq_kernel(float* tagged, const float* __restrict__ simLast,
                                   const float* __restrict__ q) {
  int i = blockIdx.x * 256 + threadIdx.x;
  if (i >= BB * LL * HD) return;
  tagged[i] += simLast[i / HD] * q[i];
}

__global__ void lstm_gates_kernel(const float* __restrict__ XW, const float* __restrict__ zh,
                                  float* __restrict__ h, float* __restrict__ c, int tstep) {
  int i = blockIdx.x * 256 + threadIdx.x;
  if (i >= BB * HD) return;
  int b = i / HD, j = i - b * HD;
  const float* zr = XW + ((size_t)b * LL + tstep) * H4;
  const float* zhr = zh + (size_t)b * H4;
  float zi = zr[j] + zhr[j];
  float zf = zr[HD + j] + zhr[HD + j];
  float zg = zr[2 * HD + j] + zhr[2 * HD + j];
  float zo = zr[3 * HD + j] + zhr[3 * HD + j];
  float ig = 1.f / (1.f + expf(-zi));
  float fg = 1.f / (1.f + expf(-zf));
  float gg = tanhf(zg);
  float og = 1.f / (1.f + expf(-zo));
  float cn = fg * c[i] + ig * gg;
  c[i] = cn;
  h[i] = og * tanhf(cn);
}

__global__ void rnn_combine_kernel(const float* __restrict__ eW, const float* __restrict__ tmp,
                                   float* __restrict__ hx, float* __restrict__ hidden, int iter) {
  int i = blockIdx.x * 256 + threadIdx.x;
  if (i >= BB * HD) return;
  float v = fmaxf(eW[i] + tmp[i], 0.f);
  hx[i] = v;
  int b = i / HD, j = i - b * HD;
  hidden[((size_t)b * 4 + iter) * HD + j] = v;
}

__global__ void attn_kernel(const float* __restrict__ tagged, const float* __restrict__ hidden,
                            float* __restrict__ instrs) {
  int b = blockIdx.x, t = threadIdx.x;  // 128 threads
  __shared__ float tg[LL * HD];
  __shared__ float hd[4 * HD];
  __shared__ float sc[4 * LL];
  for (int i = t; i < LL * HD; i += 128) tg[i] = tagged[(size_t)b * LL * HD + i];
  for (int i = t; i < 4 * HD; i += 128) hd[i] = hidden[(size_t)b * 4 * HD + i];
  __syncthreads();
  if (t < 4 * LL) {
    int i = t / LL, l = t - (t / LL) * LL;
    float s = 0.f;
    for (int h = 0; h < HD; ++h) s += hd[i * HD + h] * tg[l * HD + h];
    sc[t] = s;
  }
  __syncthreads();
  if (t < 4) {
    float m = -1e30f;
    for (int l = 0; l < LL; ++l) m = fmaxf(m, sc[t * LL + l]);
    float ssum = 0.f;
    for (int l = 0; l < LL; ++l) { float e = expf(sc[t * LL + l] - m); sc[t * LL + l] = e; ssum += e; }
    float inv = 1.f / ssum;
    for (int l = 0; l < LL; ++l) sc[t * LL + l] *= inv;
  }
  __syncthreads();
  for (int h = t; h < HD; h += 128) {
    #pragma unroll
    for (int i = 0; i < 4; ++i) {
      float s = 0.f;
      for (int l = 0; l < LL; ++l) s += sc[i * LL + l] * tg[l * HD + h];
      instrs[((size_t)b * 4 + i) * HD + h] = s;
    }
  }
}

__global__ void psim_kernel(const float* __restrict__ instrs, const float* __restrict__ pe,
                            float* __restrict__ psim) {
  int b = blockIdx.x, t = threadIdx.x;  // 64 threads
  __shared__ float sc[36];
  if (t < 36) {
    int i = t / 9, c = t - (t / 9) * 9;
    const float* x = instrs + ((size_t)b * 4 + i) * HD;
    const float* pr = pe + (size_t)c * HD;
    float s = 0.f;
    for (int h = 0; h < HD; ++h) s += x[h] * pr[h];
    sc[t] = s;
  }
  __syncthreads();
  if (t < 4) {
    float m = -1e30f;
    for (int c = 0; c < 9; ++c) m = fmaxf(m, sc[t * 9 + c]);
    float e[9], ssum = 0.f;
    for (int c = 0; c < 9; ++c) { e[c] = expf(sc[t * 9 + c] - m); ssum += e[c]; }
    float inv = 1.f / ssum;
    for (int c = 0; c < 9; ++c) psim[((size_t)b * 4 + t) * 9 + c] = e[c] * inv;
  }
}

// ---------------- heavy per-step kernels ----------------
// nscore[n] = dot(elu(sum_{p,h} a[p]*x[h]*attrs[n,p,h]*Wp[p,h,k]), w_ns)
__global__ __launch_bounds__(320) void knode_kernel(
    const float* __restrict__ attrs, const float* __restrict__ Wp,
    const float* __restrict__ instrs, const float* __restrict__ psim,
    const float* __restrict__ w_ns, float* __restrict__ nscore, int step) {
  const int t = threadIdx.x;
  const int n0 = blockIdx.x * 16;
  const int b = n0 >> 9;  // 512 nodes per graph, contiguous
  __shared__ float ax[PP * HD];
  __shared__ __align__(16) float As[16 * HD];
  __shared__ float part[5][16];
  const float* x = instrs + ((size_t)b * 4 + step) * HD;
  const float* av = psim + ((size_t)b * 4 + step) * 9;
  for (int i = t; i < PP * HD; i += 320) {
    int p = i / HD;
    ax[i] = av[p] * x[i - p * HD];
  }
  float acc[16];
  #pragma unroll
  for (int g = 0; g < 16; ++g) acc[g] = 0.f;
  const int kc = (t < HD) ? t : 0;
  for (int chunk = 0; chunk < PP; ++chunk) {
    __syncthreads();
    if (t < HD) {
      #pragma unroll
      for (int g = 0; g < 16; ++g)
        As[g * HD + t] = attrs[(size_t)(n0 + g) * (PP * HD) + chunk * HD + t] * ax[chunk * HD + t];
    }
    __syncthreads();
    const float* wp = Wp + (size_t)(chunk * HD) * HD + kc;
    const float4* As4 = (const float4*)As;
    for (int kk4 = 0; kk4 < HD / 4; ++kk4) {
      float w0 = wp[(kk4 * 4 + 0) * HD];
      float w1 = wp[(kk4 * 4 + 1) * HD];
      float w2 = wp[(kk4 * 4 + 2) * HD];
      float w3 = wp[(kk4 * 4 + 3) * HD];
      #pragma unroll
      for (int g = 0; g < 16; ++g) {
        float4 a = As4[g * (HD / 4) + kk4];
        acc[g] += a.x * w0 + a.y * w1 + a.z * w2 + a.w * w3;
      }
    }
  }
  const float wv = (t < HD) ? w_ns[t] : 0.f;
  int wave = t >> 6, lane = t & 63;
  #pragma unroll
  for (int g = 0; g < 16; ++g) {
    float v = acc[g];
    v = v > 0.f ? v : expm1f(v);
    v *= wv;
    #pragma unroll
    for (int o = 32; o; o >>= 1) v += __shfl_down(v, o, 64);
    if (lane == 0) part[wave][g] = v;
  }
  __syncthreads();
  if (t < 16) {
    nscore[n0 + t] = part[0][t] + part[1][t] + part[2][t] + part[3][t] + part[4][t];
  }
}

// escal[e] = dot(elu((instr[b]*edge_attrs[e]) @ We), w_rs)
__global__ __launch_bounds__(320) void kedge_kernel(
    const float* __restrict__ eattrs, const float* __restrict__ We,
    const float* __restrict__ instrs, const float* __restrict__ w_rs,
    float* __restrict__ escal, int step) {
  const int t = threadIdx.x;
  const int e0 = blockIdx.x * 16;
  const int b = e0 >> 12;  // 4096 edges per graph, contiguous
  __shared__ float xs[HD];
  __shared__ __align__(16) float As[16 * HD];
  __shared__ float part[5][16];
  const float* x = instrs + ((size_t)b * 4 + step) * HD;
  if (t < HD) xs[t] = x[t];
  __syncthreads();
  if (t < HD) {
    #pragma unroll
    for (int g = 0; g < 16; ++g)
      As[g * HD + t] = eattrs[(size_t)(e0 + g) * HD + t] * xs[t];
  }
  __syncthreads();
  const int kc = (t < HD) ? t : 0;
  float acc[16];
  #pragma unroll
  for (int g = 0; g < 16; ++g) acc[g] = 0.f;
  const float* wb = We + kc;
  const float4* As4 = (const float4*)As;
  for (int kk4 = 0; kk4 < HD / 4; ++kk4) {
    float w0 = wb[(kk4 * 4 + 0) * HD];
    float w1 = wb[(kk4 * 4 + 1) * HD];
    float w2 = wb[(kk4 * 4 + 2) * HD];
    float w3 = wb[(kk4 * 4 + 3) * HD];
    #pragma unroll
    for (int g = 0; g < 16; ++g) {
      float4 a = As4[g * (HD / 4) + kk4];
      acc[g] += a.x * w0 + a.y * w1 + a.z * w2 + a.w * w3;
    }
  }
  const float wv = (t < HD) ? w_rs[t] : 0.f;
  int wave = t >> 6, lane = t & 63;
  #pragma unroll
  for (int g = 0; g < 16; ++g) {
    float v = acc[g];
    v = v > 0.f ? v : expm1f(v);
    v *= wv;
    #pragma unroll
    for (int o = 32; o; o >>= 1) v += __shfl_down(v, o, 64);
    if (lane == 0) part[wave][g] = v;
  }
  __syncthreads();
  if (t < 16) {
    escal[e0 + t] = part[0][t] + part[1][t] + part[2][t] + part[3][t] + part[4][t];
  }
}

__global__ void scatter_kernel(const float* __restrict__ escal, const float* __restrict__ dist,
                               const int* __restrict__ esrc, const int* __restrict__ edst,
                               float* __restrict__ mscore) {
  int e = blockIdx.x * 256 + threadIdx.x;
  if (e < EE) atomicAdd(&mscore[edst[e]], dist[esrc[e]] * escal[e]);
}

__global__ __launch_bounds__(512) void seg_update_kernel(
    const float* __restrict__ nscore, const float* __restrict__ mscore,
    const float* __restrict__ psim, float* __restrict__ dist, int step) {
  int b = blockIdx.x, t = threadIdx.x;
  int n = b * NPG + t;
  __shared__ float sbuf[8];
  float ln = nscore[n], lr = mscore[n];
  float mN = blockReduce(ln, sbuf, 1);
  float mR = blockReduce(lr, sbuf, 1);
  float en = expf(ln - mN), er = expf(lr - mR);
  float sN = blockReduce(en, sbuf, 0);
  float sR = blockReduce(er, sbuf, 0);
  float rs = psim[((size_t)b * 4 + step) * 9 + 8];
  dist[n] = rs * (er / sR) + (1.f - rs) * (en / sN);
}

// Abp[b,p,h] = sum_{n in graph b} dist[n] * attrs[n,p,h]
__global__ void abp_kernel(const float* __restrict__ attrs, const float* __restrict__ dist,
                           float* __restrict__ Abp) {
  int b = blockIdx.y, chunk = blockIdx.x, t = threadIdx.x;  // 10 chunks x 240 dims
  if (t >= 240) return;
  int d = chunk * 240 + t;
  const float* ap = attrs + (size_t)b * NPG * (PP * HD) + d;
  const float* dp = dist + (size_t)b * NPG;
  float acc = 0.f;
  for (int n = 0; n < NPG; ++n) acc += dp[n] * ap[(size_t)n * (PP * HD)];
  Abp[(size_t)b * (PP * HD) + d] = acc;
}

__global__ void agg_feat_kernel(const float* __restrict__ Abp, const float* __restrict__ psim,
                                const float* __restrict__ enc, float* __restrict__ feat) {
  int b = blockIdx.x, t = threadIdx.x;  // 320 threads
  if (t < HD) {
    const float* pv = psim + ((size_t)b * 4 + 3) * 9;
    float s = 0.f;
    #pragma unroll
    for (int p = 0; p < PP; ++p) s += pv[p] * Abp[(size_t)b * (PP * HD) + p * HD + t];
    feat[(size_t)b * H2 + HD + t] = s;
    feat[(size_t)b * H2 + t] = enc[(size_t)b * HD + t];
  }
}

// ---------------- host launch ----------------
extern "C" void kernel_launch(void* const* d_in, const int* in_sizes, int n_in,
                              void* d_out, int out_size, void* d_ws, size_t ws_size,
                              hipStream_t stream) {
  const float* questions = (const float*)d_in[0];
  const float* cv    = (const float*)d_in[1];
  const float* pe    = (const float*)d_in[2];
  const float* attrs = (const float*)d_in[3];
  const float* eatt  = (const float*)d_in[4];
  const float* w_tag = (const float*)d_in[5];
  const float* demb  = (const float*)d_in[6];
  const float* lWih  = (const float*)d_in[7];
  const float* lWhh  = (const float*)d_in[8];
  const float* lbih  = (const float*)d_in[9];
  const float* lbhh  = (const float*)d_in[10];
  const float* rWih  = (const float*)d_in[11];
  const float* rWhh  = (const float*)d_in[12];
  const float* rbih  = (const float*)d_in[13];
  const float* rbhh  = (const float*)d_in[14];
  const float* Wp    = (const float*)d_in[15];
  const float* We    = (const float*)d_in[16];
  const float* w_ns  = (const float*)d_in[17];
  const float* w_rs  = (const float*)d_in[18];
  const float* fc1w  = (const float*)d_in[19];
  const float* fc1b  = (const float*)d_in[20];
  const float* fc2w  = (const float*)d_in[21];
  const float* fc2b  = (const float*)d_in[22];
  const int*   esrc  = (const int*)d_in[24];
  const int*   edst  = (const int*)d_in[25];
  float* out = (float*)d_out;

  float* w = (float*)d_ws;
  size_t off = 0;
  auto alloc = [&](size_t n) { float* p = w + off; off += n; return p; };
  float* ve      = alloc((size_t)CE * HD);
  float* qw      = alloc((size_t)BB * LL * HD);
  float* sim     = alloc((size_t)BB * LL * CE);
  float* simLast = alloc((size_t)BB * LL);
  float* tagged  = alloc((size_t)BB * LL * HD);
  float* XW      = alloc((size_t)BB * LL * H4);
  float* zh      = alloc((size_t)BB * H4);
  float* hbuf    = alloc((size_t)BB * HD);
  float* cbuf    = alloc((size_t)BB * HD);
  float* eW      = alloc((size_t)BB * HD);
  float* hx      = alloc((size_t)BB * HD);
  float* tmp     = alloc((size_t)BB * HD);
  float* hidden  = alloc((size_t)BB * 4 * HD);
  float* instrs  = alloc((size_t)BB * 4 * HD);
  float* psim    = alloc((size_t)BB * 4 * 9);
  float* nscore  = alloc((size_t)NN);
  float* mscore  = alloc((size_t)NN);
  float* escal   = alloc((size_t)EE);
  float* dist    = alloc((size_t)NN);
  float* Abp     = alloc((size_t)BB * PP * HD);
  float* feat    = alloc((size_t)BB * H2);
  float* t1      = alloc((size_t)BB * H2);
  (void)ws_size; (void)in_sizes; (void)n_in; (void)out_size;

  // 1. tagging
  build_ve_kernel<<<(CE * HD + 255) / 256, 256, 0, stream>>>(ve, cv, demb);
  gemm_tile<0, 0><<<dim3(10, 40), 256, 0, stream>>>(questions, HD, w_tag, HD, nullptr, qw, HD,
                                                    BB * LL, HD, HD);
  gemm_tile<1, 0><<<dim3(65, 40), 256, 0, stream>>>(qw, HD, ve, HD, nullptr, sim, CE,
                                                    BB * LL, CE, HD);
  softmax_rows_kernel<<<BB * LL, 256, 0, stream>>>(sim, simLast, CE);
  gemm_tile<0, 0><<<dim3(10, 40), 256, 0, stream>>>(sim, CE, cv, HD, nullptr, tagged, HD,
                                                    BB * LL, HD, CC);
  tagged_addq_kernel<<<(BB * LL * HD + 255) / 256, 256, 0, stream>>>(tagged, simLast, questions);

  // 2. LSTM (input projections batched over all timesteps)
  gemm_tile<1, 0><<<dim3(38, 40), 256, 0, stream>>>(tagged, HD, lWih, HD, lbih, XW, H4,
                                                    BB * LL, H4, HD);
  zero_kernel<<<(2 * BB * HD + 255) / 256, 256, 0, stream>>>(hbuf, 2 * BB * HD);  // h and c adjacent
  for (int t = 0; t < LL; ++t) {
    gemm_tile<1, 0><<<dim3(38, 2), 256, 0, stream>>>(hbuf, HD, lWhh, HD, lbhh, zh, H4,
                                                     BB, H4, HD);
    lstm_gates_kernel<<<(BB * HD + 255) / 256, 256, 0, stream>>>(XW, zh, hbuf, cbuf, t);
  }

  // 3. RNN decoder (4 hidden states)
  gemm_tile<1, 0><<<dim3(10, 2), 256, 0, stream>>>(hbuf, HD, rWih, HD, rbih, eW, HD, BB, HD, HD);
  zero_kernel<<<(BB * HD + 255) / 256, 256, 0, stream>>>(hx, BB * HD);
  for (int i = 0; i < 4; ++i) {
    gemm_tile<1, 0><<<dim3(10, 2), 256, 0, stream>>>(hx, HD, rWhh, HD, rbhh, tmp, HD, BB, HD, HD);
    rnn_combine_kernel<<<(BB * HD + 255) / 256, 256, 0, stream>>>(eW, tmp, hx, hidden, i);
  }

  // 4. attention -> instructions; property similarities for all 4 instructions
  attn_kernel<<<BB, 128, 0, stream>>>(tagged, hidden, instrs);
  psim_kernel<<<BB, 64, 0, stream>>>(instrs, pe, psim);

  // 5. message-passing refinement
  init_dist_kernel<<<(NN + 255) / 256, 256, 0, stream>>>(dist);
  for (int step = 0; step < 3; ++step) {
    knode_kernel<<<NN / 16, 320, 0, stream>>>(attrs, Wp, instrs, psim, w_ns, nscore, step);
    kedge_kernel<<<EE / 16, 320, 0, stream>>>(eatt, We, instrs, w_rs, escal, step);
    zero_kernel<<<(NN + 255) / 256, 256, 0, stream>>>(mscore, NN);
    scatter_kernel<<<(EE + 255) / 256, 256, 0, stream>>>(escal, dist, esrc, edst, mscore);
    seg_update_kernel<<<BB, 512, 0, stream>>>(nscore, mscore, psim, dist, step);
  }

  // 6. readout
  abp_kernel<<<dim3(10, BB), 256, 0, stream>>>(attrs, dist, Abp);
  agg_feat_kernel<<<BB, 320, 0, stream>>>(Abp, psim, hbuf, feat);
  gemm_tile<1, 1><<<dim3(19, 2), 256, 0, stream>>>(feat, H2, fc1w, H2, fc1b, t1, H2, BB, H2, H2);
  gemm_tile<1, 0><<<dim3(58, 2), 256, 0, stream>>>(t1, H2, fc2w, H2, fc2b, out, OUTD, BB, OUTD, H2);
}

// Round 2
// 2976.633 us; speedup vs baseline: 3.4103x; 3.4103x over previous
//
#include <hip/hip_runtime.h>
#include <math.h>

#define HD 300
#define BB 64
#define LL 20
#define PP 8
#define NN 32768
#define EE 262144
#define CC 2048
#define OUTD 1845
#define NPG 512
#define EPG 4096
#define H4 1200
#define H2 600
#define CE 2049
#define NPAD 320

typedef __attribute__((ext_vector_type(8))) short short8;
typedef __attribute__((ext_vector_type(4))) float float4v;

__device__ __forceinline__ unsigned short f2bf(float x) {
  union { float f; unsigned int u; } c; c.f = x;
  unsigned int r = c.u + 0x7fff + ((c.u >> 16) & 1);
  return (unsigned short)(r >> 16);
}

__device__ __forceinline__ float blockReduce(float v, float* sbuf, int op) {
  int t = threadIdx.x, lane = t & 63, wave = t >> 6, nw = (blockDim.x + 63) >> 6;
  #pragma unroll
  for (int o = 32; o; o >>= 1) {
    float u = __shfl_down(v, o, 64);
    v = op ? fmaxf(v, u) : (v + u);
  }
  if (lane == 0) sbuf[wave] = v;
  __syncthreads();
  float r;
  if (op) { r = sbuf[0]; for (int w2 = 1; w2 < nw; ++w2) r = fmaxf(r, sbuf[w2]); }
  else { r = 0.f; for (int w2 = 0; w2 < nw; ++w2) r += sbuf[w2]; }
  __syncthreads();
  return r;
}

// ---------------- generic tiled GEMM: C = act(A @ B(^T) + bias) ----------------
template<int TRANS_B, int ACT>
__global__ void gemm_tile(const float* __restrict__ A, int lda,
                          const float* __restrict__ B, int ldb,
                          const float* __restrict__ bias,
                          float* __restrict__ C, int ldc,
                          int M, int N, int K) {
  __shared__ float As[32][33];
  __shared__ float Bs[32][33];
  const int tid = threadIdx.x;
  const int tx = tid & 15, ty = tid >> 4;
  const int m0 = blockIdx.y * 32, n0 = blockIdx.x * 32;
  float acc00 = 0.f, acc01 = 0.f, acc10 = 0.f, acc11 = 0.f;
  for (int k0 = 0; k0 < K; k0 += 32) {
    for (int i = tid; i < 1024; i += 256) {
      int r = i >> 5, c = i & 31;
      int m = m0 + r, k = k0 + c;
      As[r][c] = (m < M && k < K) ? A[(size_t)m * lda + k] : 0.f;
    }
    if (TRANS_B) {
      for (int i = tid; i < 1024; i += 256) {
        int r = i >> 5, c = i & 31;
        int n = n0 + r, k = k0 + c;
        Bs[c][r] = (n < N && k < K) ? B[(size_t)n * ldb + k] : 0.f;
      }
    } else {
      for (int i = tid; i < 1024; i += 256) {
        int r = i >> 5, c = i & 31;
        int n = n0 + c, k = k0 + r;
        Bs[r][c] = (n < N && k < K) ? B[(size_t)k * ldb + n] : 0.f;
      }
    }
    __syncthreads();
    #pragma unroll
    for (int kk = 0; kk < 32; ++kk) {
      float a0 = As[ty * 2][kk], a1 = As[ty * 2 + 1][kk];
      float b0 = Bs[kk][tx * 2], b1 = Bs[kk][tx * 2 + 1];
      acc00 += a0 * b0; acc01 += a0 * b1; acc10 += a1 * b0; acc11 += a1 * b1;
    }
    __syncthreads();
  }
  float accs[2][2] = {{acc00, acc01}, {acc10, acc11}};
  #pragma unroll
  for (int i = 0; i < 2; ++i) {
    #pragma unroll
    for (int j = 0; j < 2; ++j) {
      int m = m0 + ty * 2 + i, n = n0 + tx * 2 + j;
      if (m < M && n < N) {
        float v = accs[i][j] + (bias ? bias[n] : 0.f);
        if (ACT == 1) v = v > 0.f ? v : expm1f(v);
        C[(size_t)m * ldc + n] = v;
      }
    }
  }
}

// ---------------- small utility kernels ----------------
__global__ void zero_kernel(float* p, int n) {
  int i = blockIdx.x * 256 + threadIdx.x;
  if (i < n) p[i] = 0.f;
}

__global__ void init_dist_kernel(float* dist) {
  int i = blockIdx.x * 256 + threadIdx.x;
  if (i < NN) dist[i] = 1.f / (float)NPG;
}

__global__ void build_ve_kernel(float* ve, const float* __restrict__ cv,
                                const float* __restrict__ demb) {
  int i = blockIdx.x * 256 + threadIdx.x;
  if (i >= CE * HD) return;
  int row = i / HD;
  ve[i] = (row < CC) ? cv[i] : demb[i - CC * HD];
}

__global__ void softmax_rows_kernel(float* __restrict__ x, float* __restrict__ lastcol, int len) {
  int row = blockIdx.x, t = threadIdx.x;
  float* p = x + (size_t)row * len;
  __shared__ float sbuf[8];
  float m = -1e30f;
  for (int i = t; i < len; i += blockDim.x) m = fmaxf(m, p[i]);
  m = blockReduce(m, sbuf, 1);
  float s = 0.f;
  for (int i = t; i < len; i += blockDim.x) { float e = expf(p[i] - m); p[i] = e; s += e; }
  s = blockReduce(s, sbuf, 0);
  float inv = 1.f / s;
  for (int i = t; i < len; i += blockDim.x) {
    float v = p[i] * inv;
    p[i] = v;
    if (lastcol && i == len - 1) lastcol[row] = v;
  }
}

__global__ void tagged_addq_kernel(float* tagged, const float* __restrict__ simLast,
                                   const float* __restrict__ q) {
  int i = blockIdx.x * 256 + threadIdx.x;
  if (i >= BB * LL * HD) return;
  tagged[i] += simLast[i / HD] * q[i];
}

__global__ void lstm_gates_kernel(const float* __restrict__ XW, const float* __restrict__ zh,
                                  float* __restrict__ h, float* __restrict__ c, int tstep) {
  int i = blockIdx.x * 256 + threadIdx.x;
  if (i >= BB * HD) return;
  int b = i / HD, j = i - b * HD;
  const float* zr = XW + ((size_t)b * LL + tstep) * H4;
  const float* zhr = zh + (size_t)b * H4;
  float zi = zr[j] + zhr[j];
  float zf = zr[HD + j] + zhr[HD + j];
  float zg = zr[2 * HD + j] + zhr[2 * HD + j];
  float zo = zr[3 * HD + j] + zhr[3 * HD + j];
  float ig = 1.f / (1.f + expf(-zi));
  float fg = 1.f / (1.f + expf(-zf));
  float gg = tanhf(zg);
  float og = 1.f / (1.f + expf(-zo));
  float cn = fg * c[i] + ig * gg;
  c[i] = cn;
  h[i] = og * tanhf(cn);
}

__global__ void rnn_combine_kernel(const float* __restrict__ eW, const float* __restrict__ tmp,
                                   float* __restrict__ hx, float* __restrict__ hidden, int iter) {
  int i = blockIdx.x * 256 + threadIdx.x;
  if (i >= BB * HD) return;
  float v = fmaxf(eW[i] + tmp[i], 0.f);
  hx[i] = v;
  int b = i / HD, j = i - b * HD;
  hidden[((size_t)b * 4 + iter) * HD + j] = v;
}

__global__ void attn_kernel(const float* __restrict__ tagged, const float* __restrict__ hidden,
                            float* __restrict__ instrs) {
  int b = blockIdx.x, t = threadIdx.x;  // 128 threads
  __shared__ float tg[LL * HD];
  __shared__ float hd[4 * HD];
  __shared__ float sc[4 * LL];
  for (int i = t; i < LL * HD; i += 128) tg[i] = tagged[(size_t)b * LL * HD + i];
  for (int i = t; i < 4 * HD; i += 128) hd[i] = hidden[(size_t)b * 4 * HD + i];
  __syncthreads();
  if (t < 4 * LL) {
    int i = t / LL, l = t - (t / LL) * LL;
    float s = 0.f;
    for (int h = 0; h < HD; ++h) s += hd[i * HD + h] * tg[l * HD + h];
    sc[t] = s;
  }
  __syncthreads();
  if (t < 4) {
    float m = -1e30f;
    for (int l = 0; l < LL; ++l) m = fmaxf(m, sc[t * LL + l]);
    float ssum = 0.f;
    for (int l = 0; l < LL; ++l) { float e = expf(sc[t * LL + l] - m); sc[t * LL + l] = e; ssum += e; }
    float inv = 1.f / ssum;
    for (int l = 0; l < LL; ++l) sc[t * LL + l] *= inv;
  }
  __syncthreads();
  for (int h = t; h < HD; h += 128) {
    #pragma unroll
    for (int i = 0; i < 4; ++i) {
      float s = 0.f;
      for (int l = 0; l < LL; ++l) s += sc[i * LL + l] * tg[l * HD + h];
      instrs[((size_t)b * 4 + i) * HD + h] = s;
    }
  }
}

__global__ void psim_kernel(const float* __restrict__ instrs, const float* __restrict__ pe,
                            float* __restrict__ psim) {
  int b = blockIdx.x, t = threadIdx.x;  // 64 threads
  __shared__ float sc[36];
  if (t < 36) {
    int i = t / 9, c = t - (t / 9) * 9;
    const float* x = instrs + ((size_t)b * 4 + i) * HD;
    const float* pr = pe + (size_t)c * HD;
    float s = 0.f;
    for (int h = 0; h < HD; ++h) s += x[h] * pr[h];
    sc[t] = s;
  }
  __syncthreads();
  if (t < 4) {
    float m = -1e30f;
    for (int c = 0; c < 9; ++c) m = fmaxf(m, sc[t * 9 + c]);
    float e[9], ssum = 0.f;
    for (int c = 0; c < 9; ++c) { e[c] = expf(sc[t * 9 + c] - m); ssum += e[c]; }
    float inv = 1.f / ssum;
    for (int c = 0; c < 9; ++c) psim[((size_t)b * 4 + t) * 9 + c] = e[c] * inv;
  }
}

// ---------------- weight prep for MFMA score kernels ----------------
// Wpt[n][kk] = bf16(Wp[kk][n]) for n<300 else 0   (320 x 2400)
__global__ void build_wpt_kernel(const float* __restrict__ Wp, short* __restrict__ Wpt) {
  int i = blockIdx.x * 256 + threadIdx.x;
  if (i >= NPAD * 2400) return;
  int n = i / 2400, kk = i - n * 2400;
  float v = (n < HD) ? Wp[(size_t)kk * HD + n] : 0.f;
  Wpt[i] = (short)f2bf(v);
}

// Wet[n][h] = bf16(We[h][n]) for n<300,h<300 else 0   (320 x 320)
__global__ void build_wet_kernel(const float* __restrict__ We, short* __restrict__ Wet) {
  int i = blockIdx.x * 256 + threadIdx.x;
  if (i >= NPAD * NPAD) return;
  int n = i / NPAD, h = i - n * NPAD;
  float v = (n < HD && h < HD) ? We[(size_t)h * HD + n] : 0.f;
  Wet[i] = (short)f2bf(v);
}

__global__ void build_wpad_kernel(const float* __restrict__ w1, const float* __restrict__ w2,
                                  float* __restrict__ p1, float* __restrict__ p2) {
  int i = threadIdx.x + blockIdx.x * 64;
  if (i < NPAD) { p1[i] = (i < HD) ? w1[i] : 0.f; p2[i] = (i < HD) ? w2[i] : 0.f; }
}

// per-step scale vectors: ax[b][kk]=psim_p*instr_h (64x2400), xe[b][h]=instr_h (64x320, padded)
__global__ void build_scales_kernel(const float* __restrict__ instrs, const float* __restrict__ psim,
                                    float* __restrict__ ax, float* __restrict__ xe, int step) {
  int i = blockIdx.x * 256 + threadIdx.x;
  if (i < BB * 2400) {
    int b = i / 2400, kk = i - b * 2400, p = kk / HD, h = kk - p * HD;
    ax[i] = psim[((size_t)b * 4 + step) * 9 + p] * instrs[((size_t)b * 4 + step) * HD + h];
  } else {
    int j = i - BB * 2400;
    if (j < BB * NPAD) {
      int b = j / NPAD, h = j - b * NPAD;
      xe[j] = (h < HD) ? instrs[((size_t)b * 4 + step) * HD + h] : 0.f;
    }
  }
}

// ---------------- fused MFMA score GEMM ----------------
// out[row] += sum_k elu( sum_kk (A[row,kk]*scale[b,kk]) * Bt[k][kk] ) * wout[k]
// A: fp32 (M x lda), scale: fp32 per batch (SK), Bt: bf16 (NPAD x KPAD), out: atomicAdd.
__global__ __launch_bounds__(256) void score_mfma_kernel(
    const float* __restrict__ A, int lda, int K, int KPAD,
    const float* __restrict__ scale, int SK, int bshift,
    const short* __restrict__ Bt, const float* __restrict__ wout,
    float* __restrict__ out) {
  __shared__ __align__(16) short As[64 * 40];    // row stride 40 ushorts (80B)
  __shared__ __align__(16) short Bs[NPAD * 40];
  const int tid = threadIdx.x;
  const int row0 = blockIdx.x * 64;
  const int b = row0 >> bshift;
  const int l15 = tid & 15, l4 = (tid >> 4) & 3, wid = tid >> 6;
  const int ncol0 = wid * 80;

  float4v acc[4][5];
  #pragma unroll
  for (int m = 0; m < 4; ++m)
    #pragma unroll
    for (int n = 0; n < 5; ++n) acc[m][n] = (float4v){0.f, 0.f, 0.f, 0.f};

  const int ar = tid >> 2;            // A-stage row 0..63
  const int acg = (tid & 3) * 8;      // A-stage col group
  const float* Arow = A + (size_t)(row0 + ar) * lda;
  const float* srow = scale + (size_t)b * SK;

  for (int kt = 0; kt < KPAD; kt += 32) {
    // ---- fetch A (64x32 fp32, scaled, -> bf16) ----
    int k = kt + acg;
    float4 v0 = {0.f, 0.f, 0.f, 0.f}, v1 = {0.f, 0.f, 0.f, 0.f};
    if (k < K)     v0 = *(const float4*)(Arow + k);
    if (k + 4 < K) v1 = *(const float4*)(Arow + k + 4);
    float4 s0 = *(const float4*)(srow + k);
    float4 s1 = *(const float4*)(srow + k + 4);
    short8 av;
    av[0] = (short)f2bf(v0.x * s0.x); av[1] = (short)f2bf(v0.y * s0.y);
    av[2] = (short)f2bf(v0.z * s0.z); av[3] = (short)f2bf(v0.w * s0.w);
    av[4] = (short)f2bf(v1.x * s1.x); av[5] = (short)f2bf(v1.y * s1.y);
    av[6] = (short)f2bf(v1.z * s1.z); av[7] = (short)f2bf(v1.w * s1.w);
    // ---- fetch B (320x32 bf16) ----
    short8 bv[5];
    #pragma unroll
    for (int it = 0; it < 5; ++it) {
      int idx = it * 256 + tid;
      int n = idx >> 2, part = (idx & 3) * 8;
      bv[it] = *(const short8*)(Bt + (size_t)n * KPAD + kt + part);
    }
    __syncthreads();   // previous iteration's reads complete
    *(short8*)&As[ar * 40 + acg] = av;
    #pragma unroll
    for (int it = 0; it < 5; ++it) {
      int idx = it * 256 + tid;
      int n = idx >> 2, part = (idx & 3) * 8;
      *(short8*)&Bs[n * 40 + part] = bv[it];
    }
    __syncthreads();   // stores visible
    short8 af[4], bf[5];
    #pragma unroll
    for (int m = 0; m < 4; ++m)
      af[m] = *(const short8*)&As[(m * 16 + l15) * 40 + l4 * 8];
    #pragma unroll
    for (int n = 0; n < 5; ++n)
      bf[n] = *(const short8*)&Bs[(ncol0 + n * 16 + l15) * 40 + l4 * 8];
    #pragma unroll
    for (int m = 0; m < 4; ++m)
      #pragma unroll
      for (int n = 0; n < 5; ++n)
        acc[m][n] = __builtin_amdgcn_mfma_f32_16x16x32_bf16(af[m], bf[n], acc[m][n], 0, 0, 0);
  }

  // ---- epilogue: elu, dot with wout, row-reduce, atomic accumulate ----
  float wv[5];
  #pragma unroll
  for (int n = 0; n < 5; ++n) wv[n] = wout[ncol0 + n * 16 + l15];
  #pragma unroll
  for (int m = 0; m < 4; ++m) {
    float s[4] = {0.f, 0.f, 0.f, 0.f};
    #pragma unroll
    for (int n = 0; n < 5; ++n) {
      #pragma unroll
      for (int r = 0; r < 4; ++r) {
        float v = acc[m][n][r];
        v = v > 0.f ? v : expm1f(v);
        s[r] += v * wv[n];
      }
    }
    #pragma unroll
    for (int r = 0; r < 4; ++r) {
      float t = s[r];
      t += __shfl_xor(t, 1, 64);
      t += __shfl_xor(t, 2, 64);
      t += __shfl_xor(t, 4, 64);
      t += __shfl_xor(t, 8, 64);
      if (l15 == 0) atomicAdd(&out[row0 + m * 16 + l4 * 4 + r], t);
    }
  }
}

__global__ void scatter_kernel(const float* __restrict__ escal, const float* __restrict__ dist,
                               const int* __restrict__ esrc, const int* __restrict__ edst,
                               float* __restrict__ mscore) {
  int e = blockIdx.x * 256 + threadIdx.x;
  if (e < EE) atomicAdd(&mscore[edst[e]], dist[esrc[e]] * escal[e]);
}

__global__ __launch_bounds__(512) void seg_update_kernel(
    const float* __restrict__ nscore, const float* __restrict__ mscore,
    const float* __restrict__ psim, float* __restrict__ dist, int step) {
  int b = blockIdx.x, t = threadIdx.x;
  int n = b * NPG + t;
  __shared__ float sbuf[8];
  float ln = nscore[n], lr = mscore[n];
  float mN = blockReduce(ln, sbuf, 1);
  float mR = blockReduce(lr, sbuf, 1);
  float en = expf(ln - mN), er = expf(lr - mR);
  float sN = blockReduce(en, sbuf, 0);
  float sR = blockReduce(er, sbuf, 0);
  float rs = psim[((size_t)b * 4 + step) * 9 + 8];
  dist[n] = rs * (er / sR) + (1.f - rs) * (en / sN);
}

// Abp[b,p,h] = sum_{n in graph b} dist[n] * attrs[n,p,h]
__global__ void abp_kernel(const float* __restrict__ attrs, const float* __restrict__ dist,
                           float* __restrict__ Abp) {
  int b = blockIdx.y, chunk = blockIdx.x, t = threadIdx.x;
  if (t >= 240) return;
  int d = chunk * 240 + t;
  const float* ap = attrs + (size_t)b * NPG * (PP * HD) + d;
  const float* dp = dist + (size_t)b * NPG;
  float acc = 0.f;
  for (int n = 0; n < NPG; ++n) acc += dp[n] * ap[(size_t)n * (PP * HD)];
  Abp[(size_t)b * (PP * HD) + d] = acc;
}

__global__ void agg_feat_kernel(const float* __restrict__ Abp, const float* __restrict__ psim,
                                const float* __restrict__ enc, float* __restrict__ feat) {
  int b = blockIdx.x, t = threadIdx.x;
  if (t < HD) {
    const float* pv = psim + ((size_t)b * 4 + 3) * 9;
    float s = 0.f;
    #pragma unroll
    for (int p = 0; p < PP; ++p) s += pv[p] * Abp[(size_t)b * (PP * HD) + p * HD + t];
    feat[(size_t)b * H2 + HD + t] = s;
    feat[(size_t)b * H2 + t] = enc[(size_t)b * HD + t];
  }
}

// ---------------- host launch ----------------
extern "C" void kernel_launch(void* const* d_in, const int* in_sizes, int n_in,
                              void* d_out, int out_size, void* d_ws, size_t ws_size,
                              hipStream_t stream) {
  const float* questions = (const float*)d_in[0];
  const float* cv    = (const float*)d_in[1];
  const float* pe    = (const float*)d_in[2];
  const float* attrs = (const float*)d_in[3];
  const float* eatt  = (const float*)d_in[4];
  const float* w_tag = (const float*)d_in[5];
  const float* demb  = (const float*)d_in[6];
  const float* lWih  = (const float*)d_in[7];
  const float* lWhh  = (const float*)d_in[8];
  const float* lbih  = (const float*)d_in[9];
  const float* lbhh  = (const float*)d_in[10];
  const float* rWih  = (const float*)d_in[11];
  const float* rWhh  = (const float*)d_in[12];
  const float* rbih  = (const float*)d_in[13];
  const float* rbhh  = (const float*)d_in[14];
  const float* Wp    = (const float*)d_in[15];
  const float* We    = (const float*)d_in[16];
  const float* w_ns  = (const float*)d_in[17];
  const float* w_rs  = (const float*)d_in[18];
  const float* fc1w  = (const float*)d_in[19];
  const float* fc1b  = (const float*)d_in[20];
  const float* fc2w  = (const float*)d_in[21];
  const float* fc2b  = (const float*)d_in[22];
  const int*   esrc  = (const int*)d_in[24];
  const int*   edst  = (const int*)d_in[25];
  float* out = (float*)d_out;

  float* w = (float*)d_ws;
  size_t off = 0;
  auto alloc = [&](size_t n) { float* p = w + off; off += n; return p; };
  float* ve      = alloc((size_t)CE * HD);
  float* qw      = alloc((size_t)BB * LL * HD);
  float* sim     = alloc((size_t)BB * LL * CE);
  float* simLast = alloc((size_t)BB * LL);
  float* tagged  = alloc((size_t)BB * LL * HD);
  float* XW      = alloc((size_t)BB * LL * H4);
  float* zh      = alloc((size_t)BB * H4);
  float* hbuf    = alloc((size_t)BB * HD);
  float* cbuf    = alloc((size_t)BB * HD);
  float* eW      = alloc((size_t)BB * HD);
  float* hx      = alloc((size_t)BB * HD);
  float* tmp     = alloc((size_t)BB * HD);
  float* hidden  = alloc((size_t)BB * 4 * HD);
  float* instrs  = alloc((size_t)BB * 4 * HD);
  float* psim    = alloc((size_t)BB * 4 * 9);
  float* nscore  = alloc((size_t)NN);       // nscore, mscore, escal contiguous (zeroed in one go)
  float* mscore  = alloc((size_t)NN);
  float* escal   = alloc((size_t)EE);
  float* dist    = alloc((size_t)NN);
  float* Abp     = alloc((size_t)BB * PP * HD);
  float* feat    = alloc((size_t)BB * H2);
  float* t1      = alloc((size_t)BB * H2);
  short* Wpt     = (short*)alloc((size_t)NPAD * 2400 / 2);  // bf16 320x2400
  short* Wet     = (short*)alloc((size_t)NPAD * NPAD / 2);  // bf16 320x320
  float* wnsp    = alloc(NPAD);
  float* wrsp    = alloc(NPAD);
  float* ax      = alloc((size_t)BB * 2400);
  float* xe      = alloc((size_t)BB * NPAD);
  (void)ws_size; (void)in_sizes; (void)n_in; (void)out_size;

  // 0. weight prep for MFMA kernels
  build_wpt_kernel<<<(NPAD * 2400 + 255) / 256, 256, 0, stream>>>(Wp, Wpt);
  build_wet_kernel<<<(NPAD * NPAD + 255) / 256, 256, 0, stream>>>(We, Wet);
  build_wpad_kernel<<<5, 64, 0, stream>>>(w_ns, w_rs, wnsp, wrsp);

  // 1. tagging
  build_ve_kernel<<<(CE * HD + 255) / 256, 256, 0, stream>>>(ve, cv, demb);
  gemm_tile<0, 0><<<dim3(10, 40), 256, 0, stream>>>(questions, HD, w_tag, HD, nullptr, qw, HD,
                                                    BB * LL, HD, HD);
  gemm_tile<1, 0><<<dim3(65, 40), 256, 0, stream>>>(qw, HD, ve, HD, nullptr, sim, CE,
                                                    BB * LL, CE, HD);
  softmax_rows_kernel<<<BB * LL, 256, 0, stream>>>(sim, simLast, CE);
  gemm_tile<0, 0><<<dim3(10, 40), 256, 0, stream>>>(sim, CE, cv, HD, nullptr, tagged, HD,
                                                    BB * LL, HD, CC);
  tagged_addq_kernel<<<(BB * LL * HD + 255) / 256, 256, 0, stream>>>(tagged, simLast, questions);

  // 2. LSTM
  gemm_tile<1, 0><<<dim3(38, 40), 256, 0, stream>>>(tagged, HD, lWih, HD, lbih, XW, H4,
                                                    BB * LL, H4, HD);
  zero_kernel<<<(2 * BB * HD + 255) / 256, 256, 0, stream>>>(hbuf, 2 * BB * HD);
  for (int t = 0; t < LL; ++t) {
    gemm_tile<1, 0><<<dim3(38, 2), 256, 0, stream>>>(hbuf, HD, lWhh, HD, lbhh, zh, H4,
                                                     BB, H4, HD);
    lstm_gates_kernel<<<(BB * HD + 255) / 256, 256, 0, stream>>>(XW, zh, hbuf, cbuf, t);
  }

  // 3. RNN decoder
  gemm_tile<1, 0><<<dim3(10, 2), 256, 0, stream>>>(hbuf, HD, rWih, HD, rbih, eW, HD, BB, HD, HD);
  zero_kernel<<<(BB * HD + 255) / 256, 256, 0, stream>>>(hx, BB * HD);
  for (int i = 0; i < 4; ++i) {
    gemm_tile<1, 0><<<dim3(10, 2), 256, 0, stream>>>(hx, HD, rWhh, HD, rbhh, tmp, HD, BB, HD, HD);
    rnn_combine_kernel<<<(BB * HD + 255) / 256, 256, 0, stream>>>(eW, tmp, hx, hidden, i);
  }

  // 4. attention + property similarities
  attn_kernel<<<BB, 128, 0, stream>>>(tagged, hidden, instrs);
  psim_kernel<<<BB, 64, 0, stream>>>(instrs, pe, psim);

  // 5. message-passing refinement (MFMA score kernels)
  init_dist_kernel<<<(NN + 255) / 256, 256, 0, stream>>>(dist);
  for (int step = 0; step < 3; ++step) {
    build_scales_kernel<<<(BB * (2400 + NPAD) + 255) / 256, 256, 0, stream>>>(instrs, psim, ax, xe, step);
    zero_kernel<<<(NN + NN + EE + 255) / 256, 256, 0, stream>>>(nscore, NN + NN + EE);
    score_mfma_kernel<<<NN / 64, 256, 0, stream>>>(attrs, 2400, 2400, 2400, ax, 2400, 9,
                                                   Wpt, wnsp, nscore);
    score_mfma_kernel<<<EE / 64, 256, 0, stream>>>(eatt, HD, HD, NPAD, xe, NPAD, 12,
                                                   Wet, wrsp, escal);
    scatter_kernel<<<(EE + 255) / 256, 256, 0, stream>>>(escal, dist, esrc, edst, mscore);
    seg_update_kernel<<<BB, 512, 0, stream>>>(nscore, mscore, psim, dist, step);
  }

  // 6. readout
  abp_kernel<<<dim3(10, BB), 256, 0, stream>>>(attrs, dist, Abp);
  agg_feat_kernel<<<BB, 320, 0, stream>>>(Abp, psim, hbuf, feat);
  gemm_tile<1, 1><<<dim3(19, 2), 256, 0, stream>>>(feat, H2, fc1w, H2, fc1b, t1, H2, BB, H2, H2);
  gemm_tile<1, 0><<<dim3(58, 2), 256, 0, stream>>>(t1, H2, fc2w, H2, fc2b, out, OUTD, BB, OUTD, H2);
}